// Round 5
// baseline (735.470 us; speedup 1.0000x reference)
//
#include <hip/hip_runtime.h>
#include <hip/hip_bf16.h>

#define D_FEAT 64
#define NPB 128              // nodes per bucket (dst >> 7)
#define NPB_SHIFT 7
#define NL1 256              // level-1 blocks
#define MAX_NB 1024          // max buckets supported by LDS arrays
#define SCAN_T 256
#define SCAN_PER_T 8
#define SCAN_CHUNK (SCAN_T * SCAN_PER_T)   // 2048
#define SRC_BITS 17
#define SRC_MASK 0x1FFFF

// ---------- Level 1a: per-block LDS histogram of dst buckets ----------
// counts_T[k*NL1 + b + 1] = #edges of block b in bucket k  (shifted by +1 for
// exclusive scan); counts_T[0] = 0.
__global__ void mp_l1hist_kernel(const int* __restrict__ edst,
                                 int* __restrict__ counts_T,
                                 int n_edges, int nb_buckets) {
    __shared__ int hist[MAX_NB];
    int t = threadIdx.x;
    for (int k = t; k < nb_buckets; k += blockDim.x) hist[k] = 0;
    __syncthreads();
    int epb = (n_edges + NL1 - 1) / NL1;
    int lo = blockIdx.x * epb;
    int hi = min(n_edges, lo + epb);
    for (int i = lo + t; i < hi; i += blockDim.x)
        atomicAdd(&hist[edst[i] >> NPB_SHIFT], 1);
    __syncthreads();
    for (int k = t; k < nb_buckets; k += blockDim.x)
        counts_T[k * NL1 + blockIdx.x + 1] = hist[k];
    if (blockIdx.x == 0 && t == 0) counts_T[0] = 0;
}

// ---------- multi-block inclusive scan (3 kernels) ----------
__global__ void mp_scan1_kernel(int* __restrict__ a, int* __restrict__ partials, int n) {
    __shared__ int tsum[SCAN_T];
    int t = threadIdx.x;
    int base = blockIdx.x * SCAN_CHUNK + t * SCAN_PER_T;
    int v[SCAN_PER_T];
    int s = 0;
    #pragma unroll
    for (int j = 0; j < SCAN_PER_T; ++j) {
        int idx = base + j;
        v[j] = (idx < n) ? a[idx] : 0;
        s += v[j];
    }
    tsum[t] = s;
    __syncthreads();
    #pragma unroll
    for (int off = 1; off < SCAN_T; off <<= 1) {
        int u = (t >= off) ? tsum[t - off] : 0;
        __syncthreads();
        tsum[t] += u;
        __syncthreads();
    }
    if (t == SCAN_T - 1) partials[blockIdx.x] = tsum[t];
    int run = (t == 0) ? 0 : tsum[t - 1];
    #pragma unroll
    for (int j = 0; j < SCAN_PER_T; ++j) {
        int idx = base + j;
        run += v[j];
        if (idx < n) a[idx] = run;
    }
}

// single-block scan of up to 256 partials
__global__ void mp_scan2_kernel(int* __restrict__ partials, int nb) {
    __shared__ int s[256];
    int t = threadIdx.x;
    s[t] = (t < nb) ? partials[t] : 0;
    __syncthreads();
    #pragma unroll
    for (int off = 1; off < 256; off <<= 1) {
        int u = (t >= off) ? s[t - off] : 0;
        __syncthreads();
        s[t] += u;
        __syncthreads();
    }
    if (t < nb) partials[t] = s[t];
}

__global__ void mp_scan3_kernel(int* __restrict__ a, const int* __restrict__ partials, int n) {
    int b = blockIdx.x;
    if (b == 0) return;
    int off = partials[b - 1];
    int base = b * SCAN_CHUNK + threadIdx.x * SCAN_PER_T;
    #pragma unroll
    for (int j = 0; j < SCAN_PER_T; ++j) {
        int idx = base + j;
        if (idx < n) a[idx] += off;
    }
}

// ---------- Level 1b: scatter edges into bucket order via LDS cursors ----------
// elist[pos] = { src | (dst&127)<<17 , weight_bits }
__global__ void mp_l1scatter_kernel(const int* __restrict__ esrc,
                                    const int* __restrict__ edst,
                                    const float* __restrict__ ew,
                                    const int* __restrict__ counts_T,
                                    int2* __restrict__ elist,
                                    int n_edges, int nb_buckets) {
    __shared__ int cur[MAX_NB];
    int t = threadIdx.x;
    for (int k = t; k < nb_buckets; k += blockDim.x)
        cur[k] = counts_T[k * NL1 + blockIdx.x];   // exclusive offset for (k, b)
    __syncthreads();
    int epb = (n_edges + NL1 - 1) / NL1;
    int lo = blockIdx.x * epb;
    int hi = min(n_edges, lo + epb);
    for (int i = lo + t; i < hi; i += blockDim.x) {
        int d = edst[i];
        int pos = atomicAdd(&cur[d >> NPB_SHIFT], 1);
        elist[pos] = make_int2(esrc[i] | ((d & (NPB - 1)) << SRC_BITS),
                               __float_as_int(ew[i]));
    }
}

// ---------- Level 2: fused per-bucket sort+gather with LDS accumulation ----------
// One block per bucket (128 dst rows, 32KB f32 LDS acc). 4 waves stream the
// bucket's contiguous edge records; lane = feature. out = input + acc.
__global__ void mp_bucket_gather_kernel(const float* __restrict__ input,
                                        const int* __restrict__ counts_T,
                                        const int2* __restrict__ elist,
                                        float* __restrict__ out,
                                        int n_nodes, int n_edges, int nb_buckets) {
    __shared__ float acc[NPB][D_FEAT];   // 32 KiB
    int k = blockIdx.x;
    int t = threadIdx.x;
    int wave = t >> 6, lane = t & 63;

    // zero accumulators
    #pragma unroll
    for (int j = 0; j < (NPB * D_FEAT) / 256; ++j)
        ((float*)acc)[j * 256 + t] = 0.0f;
    __syncthreads();

    int base = counts_T[k * NL1];
    int end  = (k + 1 < nb_buckets) ? counts_T[(k + 1) * NL1] : n_edges;
    int cnt  = end - base;

    int nfull = cnt & ~15;   // groups of 16 edges (4 per wave)
    for (int j = wave * 4; j < nfull; j += 16) {
        int i = base + j;
        int2 r0 = elist[i], r1 = elist[i + 1], r2 = elist[i + 2], r3 = elist[i + 3];
        float v0 = input[(r0.x & SRC_MASK) * D_FEAT + lane] * __int_as_float(r0.y);
        float v1 = input[(r1.x & SRC_MASK) * D_FEAT + lane] * __int_as_float(r1.y);
        float v2 = input[(r2.x & SRC_MASK) * D_FEAT + lane] * __int_as_float(r2.y);
        float v3 = input[(r3.x & SRC_MASK) * D_FEAT + lane] * __int_as_float(r3.y);
        atomicAdd(&acc[r0.x >> SRC_BITS][lane], v0);
        atomicAdd(&acc[r1.x >> SRC_BITS][lane], v1);
        atomicAdd(&acc[r2.x >> SRC_BITS][lane], v2);
        atomicAdd(&acc[r3.x >> SRC_BITS][lane], v3);
    }
    for (int j = nfull + wave; j < cnt; j += 4) {
        int2 r = elist[base + j];
        float v = input[(r.x & SRC_MASK) * D_FEAT + lane] * __int_as_float(r.y);
        atomicAdd(&acc[r.x >> SRC_BITS][lane], v);
    }
    __syncthreads();

    // write out = input + acc, coalesced
    for (int r = wave; r < NPB; r += 4) {
        int g = k * NPB + r;
        if (g < n_nodes) {
            long long o = (long long)g * D_FEAT + lane;
            out[o] = input[o] + acc[r][lane];
        }
    }
}

// ---------- fallback path (atomic scatter) ----------
__global__ void mp_copy_kernel(const float4* __restrict__ in,
                               float4* __restrict__ out, int n4) {
    int i = blockIdx.x * blockDim.x + threadIdx.x;
    if (i < n4) out[i] = in[i];
}

__global__ void mp_scatter_kernel(const float* __restrict__ input,
                                  const float* __restrict__ ew,
                                  const int* __restrict__ esrc,
                                  const int* __restrict__ edst,
                                  float* __restrict__ out, int n_edges) {
    int tid = blockIdx.x * blockDim.x + threadIdx.x;
    int e = tid >> 6;
    if (e >= n_edges) return;
    int lane = tid & 63;
    float v = input[(long long)esrc[e] * D_FEAT + lane] * ew[e];
    atomicAdd(&out[(long long)edst[e] * D_FEAT + lane], v);
}

extern "C" void kernel_launch(void* const* d_in, const int* in_sizes, int n_in,
                              void* d_out, int out_size, void* d_ws, size_t ws_size,
                              hipStream_t stream) {
    const float* input = (const float*)d_in[0];
    const float* ew    = (const float*)d_in[1];
    const int* esrc    = (const int*)d_in[2];
    const int* edst    = (const int*)d_in[3];
    float* out = (float*)d_out;

    int n_nodes = in_sizes[0] / D_FEAT;   // 100000
    int n_edges = in_sizes[1];            // 1600000

    int nb_buckets = (n_nodes + NPB - 1) / NPB;          // 782
    int n_scan = nb_buckets * NL1 + 1;                   // 200193
    int nbs = (n_scan + SCAN_CHUNK - 1) / SCAN_CHUNK;    // 98

    // ws: counts_T[n_scan] | partials[256] | pad256 | elist[E] int2
    size_t head = ((size_t)n_scan + 256) * 4;
    size_t elist_off = (head + 255) & ~(size_t)255;
    size_t needed = elist_off + (size_t)n_edges * 8;

    bool ok = (ws_size >= needed) && (nb_buckets <= MAX_NB) &&
              (n_nodes <= (1 << SRC_BITS)) && (nbs <= 256);

    if (ok) {
        int* counts_T = (int*)d_ws;
        int* partials = counts_T + n_scan;
        int2* elist   = (int2*)((char*)d_ws + elist_off);

        mp_l1hist_kernel<<<NL1, 256, 0, stream>>>(edst, counts_T, n_edges, nb_buckets);
        mp_scan1_kernel<<<nbs, SCAN_T, 0, stream>>>(counts_T, partials, n_scan);
        mp_scan2_kernel<<<1, 256, 0, stream>>>(partials, nbs);
        mp_scan3_kernel<<<nbs, SCAN_T, 0, stream>>>(counts_T, partials, n_scan);
        mp_l1scatter_kernel<<<NL1, 256, 0, stream>>>(esrc, edst, ew, counts_T,
                                                     elist, n_edges, nb_buckets);
        mp_bucket_gather_kernel<<<nb_buckets, 256, 0, stream>>>(
            input, counts_T, elist, out, n_nodes, n_edges, nb_buckets);
    } else {
        int n4 = (n_nodes * D_FEAT) / 4;
        mp_copy_kernel<<<(n4 + 255) / 256, 256, 0, stream>>>(
            (const float4*)input, (float4*)out, n4);
        long long total = (long long)n_edges * 64;
        mp_scatter_kernel<<<(int)((total + 255) / 256), 256, 0, stream>>>(
            input, ew, esrc, edst, out, n_edges);
    }
}

// Round 6
// 130.703 us; speedup vs baseline: 5.6270x; 5.6270x over previous
//
#include <hip/hip_runtime.h>
#include <hip/hip_bf16.h>

#define D_FEAT 64
#define NPB 128              // nodes per bucket (dst >> 7)
#define NPB_SHIFT 7
#define NL1 256              // level-1 blocks
#define MAX_NB 1024          // max buckets supported by LDS arrays
#define SCAN_T 256
#define SCAN_PER_T 8
#define SCAN_CHUNK (SCAN_T * SCAN_PER_T)   // 2048
#define SRC_BITS 17
#define SRC_MASK 0x1FFFF

// ---------- Level 1a: per-block LDS histogram of dst buckets ----------
// counts_T[k*NL1 + b + 1] = #edges of block b in bucket k (+1 shift for scan)
__global__ void mp_l1hist_kernel(const int* __restrict__ edst,
                                 int* __restrict__ counts_T,
                                 int n_edges, int nb_buckets) {
    __shared__ int hist[MAX_NB];
    int t = threadIdx.x;
    for (int k = t; k < nb_buckets; k += blockDim.x) hist[k] = 0;
    __syncthreads();
    int epb = (n_edges + NL1 - 1) / NL1;
    int lo = blockIdx.x * epb;
    int hi = min(n_edges, lo + epb);
    for (int i = lo + t; i < hi; i += blockDim.x)
        atomicAdd(&hist[edst[i] >> NPB_SHIFT], 1);
    __syncthreads();
    for (int k = t; k < nb_buckets; k += blockDim.x)
        counts_T[k * NL1 + blockIdx.x + 1] = hist[k];
    if (blockIdx.x == 0 && t == 0) counts_T[0] = 0;
}

// ---------- multi-block inclusive scan (3 kernels) ----------
__global__ void mp_scan1_kernel(int* __restrict__ a, int* __restrict__ partials, int n) {
    __shared__ int tsum[SCAN_T];
    int t = threadIdx.x;
    int base = blockIdx.x * SCAN_CHUNK + t * SCAN_PER_T;
    int v[SCAN_PER_T];
    int s = 0;
    #pragma unroll
    for (int j = 0; j < SCAN_PER_T; ++j) {
        int idx = base + j;
        v[j] = (idx < n) ? a[idx] : 0;
        s += v[j];
    }
    tsum[t] = s;
    __syncthreads();
    #pragma unroll
    for (int off = 1; off < SCAN_T; off <<= 1) {
        int u = (t >= off) ? tsum[t - off] : 0;
        __syncthreads();
        tsum[t] += u;
        __syncthreads();
    }
    if (t == SCAN_T - 1) partials[blockIdx.x] = tsum[t];
    int run = (t == 0) ? 0 : tsum[t - 1];
    #pragma unroll
    for (int j = 0; j < SCAN_PER_T; ++j) {
        int idx = base + j;
        run += v[j];
        if (idx < n) a[idx] = run;
    }
}

__global__ void mp_scan2_kernel(int* __restrict__ partials, int nb) {
    __shared__ int s[256];
    int t = threadIdx.x;
    s[t] = (t < nb) ? partials[t] : 0;
    __syncthreads();
    #pragma unroll
    for (int off = 1; off < 256; off <<= 1) {
        int u = (t >= off) ? s[t - off] : 0;
        __syncthreads();
        s[t] += u;
        __syncthreads();
    }
    if (t < nb) partials[t] = s[t];
}

__global__ void mp_scan3_kernel(int* __restrict__ a, const int* __restrict__ partials, int n) {
    int b = blockIdx.x;
    if (b == 0) return;
    int off = partials[b - 1];
    int base = b * SCAN_CHUNK + threadIdx.x * SCAN_PER_T;
    #pragma unroll
    for (int j = 0; j < SCAN_PER_T; ++j) {
        int idx = base + j;
        if (idx < n) a[idx] += off;
    }
}

// ---------- Level 1b: scatter edges into bucket order via LDS cursors ----------
// elistA[pos] = { src | (dst&127)<<17 , weight_bits }
__global__ void mp_l1scatter_kernel(const int* __restrict__ esrc,
                                    const int* __restrict__ edst,
                                    const float* __restrict__ ew,
                                    const int* __restrict__ counts_T,
                                    int2* __restrict__ elistA,
                                    int n_edges, int nb_buckets) {
    __shared__ int cur[MAX_NB];
    int t = threadIdx.x;
    for (int k = t; k < nb_buckets; k += blockDim.x)
        cur[k] = counts_T[k * NL1 + blockIdx.x];   // exclusive offset for (k, b)
    __syncthreads();
    int epb = (n_edges + NL1 - 1) / NL1;
    int lo = blockIdx.x * epb;
    int hi = min(n_edges, lo + epb);
    for (int i = lo + t; i < hi; i += blockDim.x) {
        int d = edst[i];
        int pos = atomicAdd(&cur[d >> NPB_SHIFT], 1);
        elistA[pos] = make_int2(esrc[i] | ((d & (NPB - 1)) << SRC_BITS),
                                __float_as_int(ew[i]));
    }
}

// ---------- Level 2: per-bucket counting sort into per-node CSR order ----------
// One block per bucket. Emits elistB (node-grouped records, src-only) and
// node_start[] (global CSR offsets). Writes stay within the bucket's ~16KB
// window -> L2-coalesced.
__global__ void mp_l2sort_kernel(const int2* __restrict__ elistA,
                                 const int* __restrict__ counts_T,
                                 int2* __restrict__ elistB,
                                 int* __restrict__ node_start,
                                 int n_nodes, int n_edges, int nb_buckets) {
    __shared__ int nh[NPB];    // per-node count -> inclusive scan
    __shared__ int cur[NPB];   // scatter cursors
    int k = blockIdx.x;
    int t = threadIdx.x;
    if (t < NPB) nh[t] = 0;
    __syncthreads();

    int base = counts_T[k * NL1];
    int end  = (k + 1 < nb_buckets) ? counts_T[(k + 1) * NL1] : n_edges;
    int cnt  = end - base;

    for (int i = t; i < cnt; i += 256)
        atomicAdd(&nh[elistA[base + i].x >> SRC_BITS], 1);
    __syncthreads();

    // inclusive scan nh[0..127] (block-wide Hillis-Steele)
    #pragma unroll
    for (int off = 1; off < NPB; off <<= 1) {
        int v = (t < NPB && t >= off) ? nh[t - off] : 0;
        __syncthreads();
        if (t < NPB) nh[t] += v;
        __syncthreads();
    }

    if (t < NPB) {
        int excl = base + ((t == 0) ? 0 : nh[t - 1]);
        cur[t] = excl;
        int g = k * NPB + t;
        if (g < n_nodes) node_start[g] = excl;
    }
    if (k == nb_buckets - 1 && t == 0) node_start[n_nodes] = n_edges;
    __syncthreads();

    for (int i = t; i < cnt; i += 256) {
        int2 r = elistA[base + i];
        int pos = atomicAdd(&cur[r.x >> SRC_BITS], 1);
        elistB[pos] = make_int2(r.x & SRC_MASK, r.y);
    }
}

// ---------- Gather: one wave per destination node ----------
__global__ void mp_gather2_kernel(const float* __restrict__ input,
                                  const int* __restrict__ node_start,
                                  const int2* __restrict__ elistB,
                                  float* __restrict__ out, int n_nodes) {
    int wid = (blockIdx.x * blockDim.x + threadIdx.x) >> 6;
    if (wid >= n_nodes) return;
    int lane = threadIdx.x & 63;
    int b = node_start[wid], e_end = node_start[wid + 1];
    float acc = input[(long long)wid * D_FEAT + lane];
    int i = b;
    for (; i + 3 < e_end; i += 4) {   // 4-way unroll for memory-level parallelism
        int2 e0 = elistB[i];
        int2 e1 = elistB[i + 1];
        int2 e2 = elistB[i + 2];
        int2 e3 = elistB[i + 3];
        float v0 = input[(long long)e0.x * D_FEAT + lane];
        float v1 = input[(long long)e1.x * D_FEAT + lane];
        float v2 = input[(long long)e2.x * D_FEAT + lane];
        float v3 = input[(long long)e3.x * D_FEAT + lane];
        acc += v0 * __int_as_float(e0.y);
        acc += v1 * __int_as_float(e1.y);
        acc += v2 * __int_as_float(e2.y);
        acc += v3 * __int_as_float(e3.y);
    }
    for (; i < e_end; ++i) {
        int2 e0 = elistB[i];
        acc += input[(long long)e0.x * D_FEAT + lane] * __int_as_float(e0.y);
    }
    out[(long long)wid * D_FEAT + lane] = acc;
}

// ---------- fallback path (atomic scatter) ----------
__global__ void mp_copy_kernel(const float4* __restrict__ in,
                               float4* __restrict__ out, int n4) {
    int i = blockIdx.x * blockDim.x + threadIdx.x;
    if (i < n4) out[i] = in[i];
}

__global__ void mp_scatter_kernel(const float* __restrict__ input,
                                  const float* __restrict__ ew,
                                  const int* __restrict__ esrc,
                                  const int* __restrict__ edst,
                                  float* __restrict__ out, int n_edges) {
    int tid = blockIdx.x * blockDim.x + threadIdx.x;
    int e = tid >> 6;
    if (e >= n_edges) return;
    int lane = tid & 63;
    float v = input[(long long)esrc[e] * D_FEAT + lane] * ew[e];
    atomicAdd(&out[(long long)edst[e] * D_FEAT + lane], v);
}

extern "C" void kernel_launch(void* const* d_in, const int* in_sizes, int n_in,
                              void* d_out, int out_size, void* d_ws, size_t ws_size,
                              hipStream_t stream) {
    const float* input = (const float*)d_in[0];
    const float* ew    = (const float*)d_in[1];
    const int* esrc    = (const int*)d_in[2];
    const int* edst    = (const int*)d_in[3];
    float* out = (float*)d_out;

    int n_nodes = in_sizes[0] / D_FEAT;   // 100000
    int n_edges = in_sizes[1];            // 1600000

    int nb_buckets = (n_nodes + NPB - 1) / NPB;          // 782
    int n_scan = nb_buckets * NL1 + 1;                   // 200193
    int nbs = (n_scan + SCAN_CHUNK - 1) / SCAN_CHUNK;    // 98

    // ws: counts_T[n_scan] | partials[256] | node_start[n_nodes+1] | pad | elistA[E] | elistB[E]
    size_t head_ints = (size_t)n_scan + 256 + (size_t)n_nodes + 1;
    size_t elist_off = (head_ints * 4 + 255) & ~(size_t)255;
    size_t needed = elist_off + 2 * (size_t)n_edges * 8;

    bool ok = (ws_size >= needed) && (nb_buckets <= MAX_NB) &&
              (n_nodes <= (1 << SRC_BITS)) && (nbs <= 256);

    if (ok) {
        int* counts_T   = (int*)d_ws;
        int* partials   = counts_T + n_scan;
        int* node_start = partials + 256;
        int2* elistA    = (int2*)((char*)d_ws + elist_off);
        int2* elistB    = elistA + n_edges;

        mp_l1hist_kernel<<<NL1, 256, 0, stream>>>(edst, counts_T, n_edges, nb_buckets);
        mp_scan1_kernel<<<nbs, SCAN_T, 0, stream>>>(counts_T, partials, n_scan);
        mp_scan2_kernel<<<1, 256, 0, stream>>>(partials, nbs);
        mp_scan3_kernel<<<nbs, SCAN_T, 0, stream>>>(counts_T, partials, n_scan);
        mp_l1scatter_kernel<<<NL1, 256, 0, stream>>>(esrc, edst, ew, counts_T,
                                                     elistA, n_edges, nb_buckets);
        mp_l2sort_kernel<<<nb_buckets, 256, 0, stream>>>(
            elistA, counts_T, elistB, node_start, n_nodes, n_edges, nb_buckets);
        long long total = (long long)n_nodes * 64;
        mp_gather2_kernel<<<(int)((total + 255) / 256), 256, 0, stream>>>(
            input, node_start, elistB, out, n_nodes);
    } else {
        int n4 = (n_nodes * D_FEAT) / 4;
        mp_copy_kernel<<<(n4 + 255) / 256, 256, 0, stream>>>(
            (const float4*)input, (float4*)out, n4);
        long long total = (long long)n_edges * 64;
        mp_scatter_kernel<<<(int)((total + 255) / 256), 256, 0, stream>>>(
            input, ew, esrc, edst, out, n_edges);
    }
}

// Round 7
// 124.984 us; speedup vs baseline: 5.8845x; 1.0458x over previous
//
#include <hip/hip_runtime.h>
#include <hip/hip_bf16.h>

#define D_FEAT 64
#define NPB 128              // nodes per bucket (dst >> 7)
#define NPB_SHIFT 7
#define NL1 256              // level-1 blocks
#define MAX_NB 1024          // max buckets supported by LDS arrays
#define SCAN_T 256
#define SCAN_PER_T 8
#define SCAN_CHUNK (SCAN_T * SCAN_PER_T)   // 2048
#define SRC_BITS 17
#define SRC_MASK 0x1FFFF

typedef unsigned int uint_t;

__device__ inline unsigned short f32_to_bf16_rn(float f) {
    uint_t x = __float_as_uint(f);
    uint_t r = (x + 0x7fffu + ((x >> 16) & 1u)) >> 16;   // round-to-nearest-even
    return (unsigned short)r;
}

// ---------- Level 1a: per-block LDS histogram of dst buckets ----------
__global__ void mp_l1hist_kernel(const int* __restrict__ edst,
                                 int* __restrict__ counts_T,
                                 int n_edges, int nb_buckets) {
    __shared__ int hist[MAX_NB];
    int t = threadIdx.x;
    for (int k = t; k < nb_buckets; k += blockDim.x) hist[k] = 0;
    __syncthreads();
    int epb = (n_edges + NL1 - 1) / NL1;
    int lo = blockIdx.x * epb;
    int hi = min(n_edges, lo + epb);
    for (int i = lo + t; i < hi; i += blockDim.x)
        atomicAdd(&hist[edst[i] >> NPB_SHIFT], 1);
    __syncthreads();
    for (int k = t; k < nb_buckets; k += blockDim.x)
        counts_T[k * NL1 + blockIdx.x + 1] = hist[k];
    if (blockIdx.x == 0 && t == 0) counts_T[0] = 0;
}

// ---------- multi-block inclusive scan (3 kernels) ----------
__global__ void mp_scan1_kernel(int* __restrict__ a, int* __restrict__ partials, int n) {
    __shared__ int tsum[SCAN_T];
    int t = threadIdx.x;
    int base = blockIdx.x * SCAN_CHUNK + t * SCAN_PER_T;
    int v[SCAN_PER_T];
    int s = 0;
    #pragma unroll
    for (int j = 0; j < SCAN_PER_T; ++j) {
        int idx = base + j;
        v[j] = (idx < n) ? a[idx] : 0;
        s += v[j];
    }
    tsum[t] = s;
    __syncthreads();
    #pragma unroll
    for (int off = 1; off < SCAN_T; off <<= 1) {
        int u = (t >= off) ? tsum[t - off] : 0;
        __syncthreads();
        tsum[t] += u;
        __syncthreads();
    }
    if (t == SCAN_T - 1) partials[blockIdx.x] = tsum[t];
    int run = (t == 0) ? 0 : tsum[t - 1];
    #pragma unroll
    for (int j = 0; j < SCAN_PER_T; ++j) {
        int idx = base + j;
        run += v[j];
        if (idx < n) a[idx] = run;
    }
}

__global__ void mp_scan2_kernel(int* __restrict__ partials, int nb) {
    __shared__ int s[256];
    int t = threadIdx.x;
    s[t] = (t < nb) ? partials[t] : 0;
    __syncthreads();
    #pragma unroll
    for (int off = 1; off < 256; off <<= 1) {
        int u = (t >= off) ? s[t - off] : 0;
        __syncthreads();
        s[t] += u;
        __syncthreads();
    }
    if (t < nb) partials[t] = s[t];
}

__global__ void mp_scan3_kernel(int* __restrict__ a, const int* __restrict__ partials, int n) {
    int b = blockIdx.x;
    if (b == 0) return;
    int off = partials[b - 1];
    int base = b * SCAN_CHUNK + threadIdx.x * SCAN_PER_T;
    #pragma unroll
    for (int j = 0; j < SCAN_PER_T; ++j) {
        int idx = base + j;
        if (idx < n) a[idx] += off;
    }
}

// ---------- Level 1b: scatter edges into bucket order via LDS cursors ----------
__global__ void mp_l1scatter_kernel(const int* __restrict__ esrc,
                                    const int* __restrict__ edst,
                                    const float* __restrict__ ew,
                                    const int* __restrict__ counts_T,
                                    int2* __restrict__ elistA,
                                    int n_edges, int nb_buckets) {
    __shared__ int cur[MAX_NB];
    int t = threadIdx.x;
    for (int k = t; k < nb_buckets; k += blockDim.x)
        cur[k] = counts_T[k * NL1 + blockIdx.x];
    __syncthreads();
    int epb = (n_edges + NL1 - 1) / NL1;
    int lo = blockIdx.x * epb;
    int hi = min(n_edges, lo + epb);
    for (int i = lo + t; i < hi; i += blockDim.x) {
        int d = edst[i];
        int pos = atomicAdd(&cur[d >> NPB_SHIFT], 1);
        elistA[pos] = make_int2(esrc[i] | ((d & (NPB - 1)) << SRC_BITS),
                                __float_as_int(ew[i]));
    }
}

// ---------- Level 2: per-bucket counting sort into per-node CSR order ----------
__global__ void mp_l2sort_kernel(const int2* __restrict__ elistA,
                                 const int* __restrict__ counts_T,
                                 int2* __restrict__ elistB,
                                 int* __restrict__ node_start,
                                 int n_nodes, int n_edges, int nb_buckets) {
    __shared__ int nh[NPB];
    __shared__ int cur[NPB];
    int k = blockIdx.x;
    int t = threadIdx.x;
    if (t < NPB) nh[t] = 0;
    __syncthreads();

    int base = counts_T[k * NL1];
    int end  = (k + 1 < nb_buckets) ? counts_T[(k + 1) * NL1] : n_edges;
    int cnt  = end - base;

    for (int i = t; i < cnt; i += 256)
        atomicAdd(&nh[elistA[base + i].x >> SRC_BITS], 1);
    __syncthreads();

    #pragma unroll
    for (int off = 1; off < NPB; off <<= 1) {
        int v = (t < NPB && t >= off) ? nh[t - off] : 0;
        __syncthreads();
        if (t < NPB) nh[t] += v;
        __syncthreads();
    }

    if (t < NPB) {
        int excl = base + ((t == 0) ? 0 : nh[t - 1]);
        cur[t] = excl;
        int g = k * NPB + t;
        if (g < n_nodes) node_start[g] = excl;
    }
    if (k == nb_buckets - 1 && t == 0) node_start[n_nodes] = n_edges;
    __syncthreads();

    for (int i = t; i < cnt; i += 256) {
        int2 r = elistA[base + i];
        int pos = atomicAdd(&cur[r.x >> SRC_BITS], 1);
        elistB[pos] = make_int2(r.x & SRC_MASK, r.y);
    }
}

// ---------- Convert input rows to packed bf16x2 (128B per row) ----------
// bfrow[node*32 + c] = bf16(x[2c]) | bf16(x[2c+1])<<16
__global__ void mp_cvt_kernel(const float2* __restrict__ in2,
                              uint_t* __restrict__ bfrow, int n) {
    int g = blockIdx.x * blockDim.x + threadIdx.x;
    if (g >= n) return;
    float2 v = in2[g];
    uint_t lo = f32_to_bf16_rn(v.x);
    uint_t hi = f32_to_bf16_rn(v.y);
    bfrow[g] = lo | (hi << 16);
}

// ---------- Gather (bf16 rows): one wave per node, split-wave 2 edges ----------
// lanes 0-31 take even edges, 32-63 odd edges; each half-wave reads a full
// 128B bf16 row coalesced (lane l5 -> feats 2*l5, 2*l5+1). 4 rows in flight
// per half. Halves combined with one shfl_xor; residual + store in f32.
__global__ void mp_gather3_kernel(const float* __restrict__ input,
                                  const uint_t* __restrict__ bfrow,
                                  const int* __restrict__ node_start,
                                  const int2* __restrict__ elistB,
                                  float* __restrict__ out, int n_nodes) {
    int wid = (blockIdx.x * blockDim.x + threadIdx.x) >> 6;
    if (wid >= n_nodes) return;
    int lane = threadIdx.x & 63;
    int h = lane >> 5;
    int l5 = lane & 31;
    int b = node_start[wid];
    int cnt = node_start[wid + 1] - b;

    float ax = 0.0f, ay = 0.0f;
    int i = h;
    for (; i + 6 < cnt; i += 8) {
        int2 r0 = elistB[b + i];
        int2 r1 = elistB[b + i + 2];
        int2 r2 = elistB[b + i + 4];
        int2 r3 = elistB[b + i + 6];
        uint_t u0 = bfrow[((uint_t)r0.x << 5) + l5];
        uint_t u1 = bfrow[((uint_t)r1.x << 5) + l5];
        uint_t u2 = bfrow[((uint_t)r2.x << 5) + l5];
        uint_t u3 = bfrow[((uint_t)r3.x << 5) + l5];
        float w0 = __int_as_float(r0.y), w1 = __int_as_float(r1.y);
        float w2 = __int_as_float(r2.y), w3 = __int_as_float(r3.y);
        ax = fmaf(__uint_as_float(u0 << 16), w0, ax);
        ay = fmaf(__uint_as_float(u0 & 0xffff0000u), w0, ay);
        ax = fmaf(__uint_as_float(u1 << 16), w1, ax);
        ay = fmaf(__uint_as_float(u1 & 0xffff0000u), w1, ay);
        ax = fmaf(__uint_as_float(u2 << 16), w2, ax);
        ay = fmaf(__uint_as_float(u2 & 0xffff0000u), w2, ay);
        ax = fmaf(__uint_as_float(u3 << 16), w3, ax);
        ay = fmaf(__uint_as_float(u3 & 0xffff0000u), w3, ay);
    }
    for (; i < cnt; i += 2) {
        int2 r = elistB[b + i];
        uint_t u = bfrow[((uint_t)r.x << 5) + l5];
        float w = __int_as_float(r.y);
        ax = fmaf(__uint_as_float(u << 16), w, ax);
        ay = fmaf(__uint_as_float(u & 0xffff0000u), w, ay);
    }
    ax += __shfl_xor(ax, 32, 64);
    ay += __shfl_xor(ay, 32, 64);
    if (h == 0) {
        float2 inp = ((const float2*)input)[((long long)wid << 5) + l5];
        float2 o;
        o.x = inp.x + ax;
        o.y = inp.y + ay;
        ((float2*)out)[((long long)wid << 5) + l5] = o;
    }
}

// ---------- Gather (f32 rows) fallback tier ----------
__global__ void mp_gather2_kernel(const float* __restrict__ input,
                                  const int* __restrict__ node_start,
                                  const int2* __restrict__ elistB,
                                  float* __restrict__ out, int n_nodes) {
    int wid = (blockIdx.x * blockDim.x + threadIdx.x) >> 6;
    if (wid >= n_nodes) return;
    int lane = threadIdx.x & 63;
    int b = node_start[wid], e_end = node_start[wid + 1];
    float acc = input[(long long)wid * D_FEAT + lane];
    int i = b;
    for (; i + 3 < e_end; i += 4) {
        int2 e0 = elistB[i];
        int2 e1 = elistB[i + 1];
        int2 e2 = elistB[i + 2];
        int2 e3 = elistB[i + 3];
        float v0 = input[(long long)e0.x * D_FEAT + lane];
        float v1 = input[(long long)e1.x * D_FEAT + lane];
        float v2 = input[(long long)e2.x * D_FEAT + lane];
        float v3 = input[(long long)e3.x * D_FEAT + lane];
        acc += v0 * __int_as_float(e0.y);
        acc += v1 * __int_as_float(e1.y);
        acc += v2 * __int_as_float(e2.y);
        acc += v3 * __int_as_float(e3.y);
    }
    for (; i < e_end; ++i) {
        int2 e0 = elistB[i];
        acc += input[(long long)e0.x * D_FEAT + lane] * __int_as_float(e0.y);
    }
    out[(long long)wid * D_FEAT + lane] = acc;
}

// ---------- last-resort fallback (atomic scatter) ----------
__global__ void mp_copy_kernel(const float4* __restrict__ in,
                               float4* __restrict__ out, int n4) {
    int i = blockIdx.x * blockDim.x + threadIdx.x;
    if (i < n4) out[i] = in[i];
}

__global__ void mp_scatter_kernel(const float* __restrict__ input,
                                  const float* __restrict__ ew,
                                  const int* __restrict__ esrc,
                                  const int* __restrict__ edst,
                                  float* __restrict__ out, int n_edges) {
    int tid = blockIdx.x * blockDim.x + threadIdx.x;
    int e = tid >> 6;
    if (e >= n_edges) return;
    int lane = tid & 63;
    float v = input[(long long)esrc[e] * D_FEAT + lane] * ew[e];
    atomicAdd(&out[(long long)edst[e] * D_FEAT + lane], v);
}

extern "C" void kernel_launch(void* const* d_in, const int* in_sizes, int n_in,
                              void* d_out, int out_size, void* d_ws, size_t ws_size,
                              hipStream_t stream) {
    const float* input = (const float*)d_in[0];
    const float* ew    = (const float*)d_in[1];
    const int* esrc    = (const int*)d_in[2];
    const int* edst    = (const int*)d_in[3];
    float* out = (float*)d_out;

    int n_nodes = in_sizes[0] / D_FEAT;   // 100000
    int n_edges = in_sizes[1];            // 1600000

    int nb_buckets = (n_nodes + NPB - 1) / NPB;          // 782
    int n_scan = nb_buckets * NL1 + 1;                   // 200193
    int nbs = (n_scan + SCAN_CHUNK - 1) / SCAN_CHUNK;    // 98

    // ws: counts_T[n_scan] | partials[256] | node_start[n+1] | pad | elistA | elistB | (bfrow)
    size_t head_ints = (size_t)n_scan + 256 + (size_t)n_nodes + 1;
    size_t elist_off = (head_ints * 4 + 255) & ~(size_t)255;
    size_t elist_bytes = (size_t)n_edges * 8;
    size_t needed_base = elist_off + 2 * elist_bytes;
    size_t bf_bytes = (size_t)n_nodes * (D_FEAT * 2);    // 128B per row
    size_t needed_ded = needed_base + bf_bytes;

    bool sort_ok = (ws_size >= needed_base) && (nb_buckets <= MAX_NB) &&
                   (n_nodes <= (1 << SRC_BITS)) && (nbs <= 256);
    bool bf_ded = sort_ok && (ws_size >= needed_ded);
    bool bf_ovl = sort_ok && !bf_ded && (bf_bytes <= elist_bytes);  // reuse elistA

    if (sort_ok) {
        int* counts_T   = (int*)d_ws;
        int* partials   = counts_T + n_scan;
        int* node_start = partials + 256;
        int2* elistA    = (int2*)((char*)d_ws + elist_off);
        int2* elistB    = elistA + n_edges;

        mp_l1hist_kernel<<<NL1, 256, 0, stream>>>(edst, counts_T, n_edges, nb_buckets);
        mp_scan1_kernel<<<nbs, SCAN_T, 0, stream>>>(counts_T, partials, n_scan);
        mp_scan2_kernel<<<1, 256, 0, stream>>>(partials, nbs);
        mp_scan3_kernel<<<nbs, SCAN_T, 0, stream>>>(counts_T, partials, n_scan);
        mp_l1scatter_kernel<<<NL1, 256, 0, stream>>>(esrc, edst, ew, counts_T,
                                                     elistA, n_edges, nb_buckets);
        mp_l2sort_kernel<<<nb_buckets, 256, 0, stream>>>(
            elistA, counts_T, elistB, node_start, n_nodes, n_edges, nb_buckets);

        long long total = (long long)n_nodes * 64;
        if (bf_ded || bf_ovl) {
            uint_t* bfrow = bf_ded ? (uint_t*)((char*)d_ws + needed_base)
                                   : (uint_t*)elistA;   // elistA dead after l2sort
            int ncvt = n_nodes * (D_FEAT / 2);
            mp_cvt_kernel<<<(ncvt + 255) / 256, 256, 0, stream>>>(
                (const float2*)input, bfrow, ncvt);
            mp_gather3_kernel<<<(int)((total + 255) / 256), 256, 0, stream>>>(
                input, bfrow, node_start, elistB, out, n_nodes);
        } else {
            mp_gather2_kernel<<<(int)((total + 255) / 256), 256, 0, stream>>>(
                input, node_start, elistB, out, n_nodes);
        }
    } else {
        int n4 = (n_nodes * D_FEAT) / 4;
        mp_copy_kernel<<<(n4 + 255) / 256, 256, 0, stream>>>(
            (const float4*)input, (float4*)out, n4);
        long long total = (long long)n_edges * 64;
        mp_scatter_kernel<<<(int)((total + 255) / 256), 256, 0, stream>>>(
            input, ew, esrc, edst, out, n_edges);
    }
}

// Round 9
// 117.596 us; speedup vs baseline: 6.2542x; 1.0628x over previous
//
#include <hip/hip_runtime.h>
#include <hip/hip_bf16.h>

#define D_FEAT 64
#define NPB 128              // nodes per bucket (dst >> 7)
#define NPB_SHIFT 7
#define NL1 256              // level-1 blocks
#define MAX_NB 1024          // max buckets supported by LDS arrays
#define SCAN_T 256
#define SCAN_PER_T 8
#define SCAN_CHUNK (SCAN_T * SCAN_PER_T)   // 2048
#define SRC_BITS 17
#define SRC_MASK 0x1FFFF

typedef unsigned int uint_t;

__device__ inline unsigned short f32_to_bf16_rn(float f) {
    uint_t x = __float_as_uint(f);
    uint_t r = (x + 0x7fffu + ((x >> 16) & 1u)) >> 16;   // round-to-nearest-even
    return (unsigned short)r;
}

// ---------- Level 1a: per-block LDS histogram of dst buckets ----------
__global__ void mp_l1hist_kernel(const int* __restrict__ edst,
                                 int* __restrict__ counts_T,
                                 int n_edges, int nb_buckets) {
    __shared__ int hist[MAX_NB];
    int t = threadIdx.x;
    for (int k = t; k < nb_buckets; k += blockDim.x) hist[k] = 0;
    __syncthreads();
    int epb = (n_edges + NL1 - 1) / NL1;
    int lo = blockIdx.x * epb;
    int hi = min(n_edges, lo + epb);
    for (int i = lo + t; i < hi; i += blockDim.x)
        atomicAdd(&hist[edst[i] >> NPB_SHIFT], 1);
    __syncthreads();
    for (int k = t; k < nb_buckets; k += blockDim.x)
        counts_T[k * NL1 + blockIdx.x + 1] = hist[k];
    if (blockIdx.x == 0 && t == 0) counts_T[0] = 0;
}

// ---------- multi-block inclusive scan (2 kernels) ----------
// scan1: per-block inclusive scan of a 2048 chunk; raw block sum -> partials[b]
__global__ void mp_scan1_kernel(int* __restrict__ a, int* __restrict__ partials, int n) {
    __shared__ int tsum[SCAN_T];
    int t = threadIdx.x;
    int base = blockIdx.x * SCAN_CHUNK + t * SCAN_PER_T;
    int v[SCAN_PER_T];
    int s = 0;
    #pragma unroll
    for (int j = 0; j < SCAN_PER_T; ++j) {
        int idx = base + j;
        v[j] = (idx < n) ? a[idx] : 0;
        s += v[j];
    }
    tsum[t] = s;
    __syncthreads();
    #pragma unroll
    for (int off = 1; off < SCAN_T; off <<= 1) {
        int u = (t >= off) ? tsum[t - off] : 0;
        __syncthreads();
        tsum[t] += u;
        __syncthreads();
    }
    if (t == SCAN_T - 1) partials[blockIdx.x] = tsum[t];
    int run = (t == 0) ? 0 : tsum[t - 1];
    #pragma unroll
    for (int j = 0; j < SCAN_PER_T; ++j) {
        int idx = base + j;
        run += v[j];
        if (idx < n) a[idx] = run;
    }
}

// scan3 (merged scan2): block b adds sum(partials[0..b-1]) to its chunk.
__global__ void mp_scan3_kernel(int* __restrict__ a, const int* __restrict__ partials, int n) {
    __shared__ int s[256];
    int b = blockIdx.x;
    if (b == 0) return;
    int t = threadIdx.x;
    s[t] = (t < b) ? partials[t] : 0;   // nbs <= 256 guaranteed
    __syncthreads();
    #pragma unroll
    for (int off = 128; off > 0; off >>= 1) {
        if (t < off) s[t] += s[t + off];
        __syncthreads();
    }
    int add = s[0];
    int base = b * SCAN_CHUNK + t * SCAN_PER_T;
    #pragma unroll
    for (int j = 0; j < SCAN_PER_T; ++j) {
        int idx = base + j;
        if (idx < n) a[idx] += add;
    }
}

// ---------- Level 1b: scatter edges into bucket order via LDS cursors ----------
__global__ void mp_l1scatter_kernel(const int* __restrict__ esrc,
                                    const int* __restrict__ edst,
                                    const float* __restrict__ ew,
                                    const int* __restrict__ counts_T,
                                    int2* __restrict__ elistA,
                                    int n_edges, int nb_buckets) {
    __shared__ int cur[MAX_NB];
    int t = threadIdx.x;
    for (int k = t; k < nb_buckets; k += blockDim.x)
        cur[k] = counts_T[k * NL1 + blockIdx.x];
    __syncthreads();
    int epb = (n_edges + NL1 - 1) / NL1;
    int lo = blockIdx.x * epb;
    int hi = min(n_edges, lo + epb);
    for (int i = lo + t; i < hi; i += blockDim.x) {
        int d = edst[i];
        int pos = atomicAdd(&cur[d >> NPB_SHIFT], 1);
        elistA[pos] = make_int2(esrc[i] | ((d & (NPB - 1)) << SRC_BITS),
                                __float_as_int(ew[i]));
    }
}

// ---------- Level 2: per-bucket counting sort into per-node CSR order ----------
__global__ void mp_l2sort_kernel(const int2* __restrict__ elistA,
                                 const int* __restrict__ counts_T,
                                 int2* __restrict__ elistB,
                                 int* __restrict__ node_start,
                                 int n_nodes, int n_edges, int nb_buckets) {
    __shared__ int nh[NPB];
    __shared__ int cur[NPB];
    int k = blockIdx.x;
    int t = threadIdx.x;
    if (t < NPB) nh[t] = 0;
    __syncthreads();

    int base = counts_T[k * NL1];
    int end  = (k + 1 < nb_buckets) ? counts_T[(k + 1) * NL1] : n_edges;
    int cnt  = end - base;

    for (int i = t; i < cnt; i += 256)
        atomicAdd(&nh[elistA[base + i].x >> SRC_BITS], 1);
    __syncthreads();

    #pragma unroll
    for (int off = 1; off < NPB; off <<= 1) {
        int v = (t < NPB && t >= off) ? nh[t - off] : 0;
        __syncthreads();
        if (t < NPB) nh[t] += v;
        __syncthreads();
    }

    if (t < NPB) {
        int excl = base + ((t == 0) ? 0 : nh[t - 1]);
        cur[t] = excl;
        int g = k * NPB + t;
        if (g < n_nodes) node_start[g] = excl;
    }
    if (k == nb_buckets - 1 && t == 0) node_start[n_nodes] = n_edges;
    __syncthreads();

    for (int i = t; i < cnt; i += 256) {
        int2 r = elistA[base + i];
        int pos = atomicAdd(&cur[r.x >> SRC_BITS], 1);
        elistB[pos] = make_int2(r.x & SRC_MASK, r.y);
    }
}

// ---------- Convert input rows to packed bf16x2 (128B per row) ----------
__global__ void mp_cvt_kernel(const float2* __restrict__ in2,
                              uint_t* __restrict__ bfrow, int n) {
    int g = blockIdx.x * blockDim.x + threadIdx.x;
    if (g >= n) return;
    float2 v = in2[g];
    uint_t lo = f32_to_bf16_rn(v.x);
    uint_t hi = f32_to_bf16_rn(v.y);
    bfrow[g] = lo | (hi << 16);
}

// ---------- Gather (bf16 rows), v2 fixed: coalesced elist + UNIFORM shfl ----------
// One wave per node. Lane l loads elistB[b+cbase+min(l,m-1)] (clamped -> all
// lanes active, no divergence). Per 16 edges: halves h=0/1 take even/odd,
// {src,w} broadcast via shfl (all-lane-uniform), 8 independent 128B row loads
// in flight per half. Tail is trip-count-uniform across halves: shfl index
// clamped to m-1, phantom edge's weight zeroed.
__global__ void mp_gather3_kernel(const float* __restrict__ input,
                                  const uint_t* __restrict__ bfrow,
                                  const int* __restrict__ node_start,
                                  const int2* __restrict__ elistB,
                                  float* __restrict__ out, int n_nodes) {
    int wid = (blockIdx.x * blockDim.x + threadIdx.x) >> 6;
    if (wid >= n_nodes) return;
    int lane = threadIdx.x & 63;
    int h = lane >> 5;
    int l5 = lane & 31;
    int b = node_start[wid];
    int cnt = node_start[wid + 1] - b;

    float ax = 0.0f, ay = 0.0f;
    for (int cbase = 0; cbase < cnt; cbase += 64) {
        int m = min(64, cnt - cbase);          // >= 1, wave-uniform
        int2 rr = elistB[b + cbase + min(lane, m - 1)];   // all lanes active
        int rx = rr.x;
        int ry = rr.y;
        int jp = 0;
        for (; jp + 16 <= m; jp += 16) {       // uniform: full 16-edge groups
            int   s[8];
            float w[8];
            uint_t u[8];
            #pragma unroll
            for (int q = 0; q < 8; ++q) {
                int jj = jp + 2 * q + h;       // < jp+16 <= m
                s[q] = __shfl(rx, jj, 64);
                w[q] = __int_as_float(__shfl(ry, jj, 64));
            }
            #pragma unroll
            for (int q = 0; q < 8; ++q)
                u[q] = bfrow[((uint_t)s[q] << 5) + l5];
            #pragma unroll
            for (int q = 0; q < 8; ++q) {
                ax = fmaf(__uint_as_float(u[q] << 16), w[q], ax);
                ay = fmaf(__uint_as_float(u[q] & 0xffff0000u), w[q], ay);
            }
        }
        // uniform tail: both halves run identical trip count; clamp shfl lane,
        // zero phantom weight.
        for (int j = jp; j < m; j += 2) {
            int jj = j + h;
            int jc = (jj < m) ? jj : (m - 1);
            int sj = __shfl(rx, jc, 64);
            float wj = __int_as_float(__shfl(ry, jc, 64));
            if (jj >= m) wj = 0.0f;
            uint_t uj = bfrow[((uint_t)sj << 5) + l5];
            ax = fmaf(__uint_as_float(uj << 16), wj, ax);
            ay = fmaf(__uint_as_float(uj & 0xffff0000u), wj, ay);
        }
    }
    ax += __shfl_xor(ax, 32, 64);
    ay += __shfl_xor(ay, 32, 64);
    if (h == 0) {
        float2 inp = ((const float2*)input)[((long long)wid << 5) + l5];
        float2 o;
        o.x = inp.x + ax;
        o.y = inp.y + ay;
        ((float2*)out)[((long long)wid << 5) + l5] = o;
    }
}

// ---------- Gather (f32 rows) fallback tier ----------
__global__ void mp_gather2_kernel(const float* __restrict__ input,
                                  const int* __restrict__ node_start,
                                  const int2* __restrict__ elistB,
                                  float* __restrict__ out, int n_nodes) {
    int wid = (blockIdx.x * blockDim.x + threadIdx.x) >> 6;
    if (wid >= n_nodes) return;
    int lane = threadIdx.x & 63;
    int b = node_start[wid], e_end = node_start[wid + 1];
    float acc = input[(long long)wid * D_FEAT + lane];
    int i = b;
    for (; i + 3 < e_end; i += 4) {
        int2 e0 = elistB[i];
        int2 e1 = elistB[i + 1];
        int2 e2 = elistB[i + 2];
        int2 e3 = elistB[i + 3];
        float v0 = input[(long long)e0.x * D_FEAT + lane];
        float v1 = input[(long long)e1.x * D_FEAT + lane];
        float v2 = input[(long long)e2.x * D_FEAT + lane];
        float v3 = input[(long long)e3.x * D_FEAT + lane];
        acc += v0 * __int_as_float(e0.y);
        acc += v1 * __int_as_float(e1.y);
        acc += v2 * __int_as_float(e2.y);
        acc += v3 * __int_as_float(e3.y);
    }
    for (; i < e_end; ++i) {
        int2 e0 = elistB[i];
        acc += input[(long long)e0.x * D_FEAT + lane] * __int_as_float(e0.y);
    }
    out[(long long)wid * D_FEAT + lane] = acc;
}

// ---------- last-resort fallback (atomic scatter) ----------
__global__ void mp_copy_kernel(const float4* __restrict__ in,
                               float4* __restrict__ out, int n4) {
    int i = blockIdx.x * blockDim.x + threadIdx.x;
    if (i < n4) out[i] = in[i];
}

__global__ void mp_scatter_kernel(const float* __restrict__ input,
                                  const float* __restrict__ ew,
                                  const int* __restrict__ esrc,
                                  const int* __restrict__ edst,
                                  float* __restrict__ out, int n_edges) {
    int tid = blockIdx.x * blockDim.x + threadIdx.x;
    int e = tid >> 6;
    if (e >= n_edges) return;
    int lane = tid & 63;
    float v = input[(long long)esrc[e] * D_FEAT + lane] * ew[e];
    atomicAdd(&out[(long long)edst[e] * D_FEAT + lane], v);
}

extern "C" void kernel_launch(void* const* d_in, const int* in_sizes, int n_in,
                              void* d_out, int out_size, void* d_ws, size_t ws_size,
                              hipStream_t stream) {
    const float* input = (const float*)d_in[0];
    const float* ew    = (const float*)d_in[1];
    const int* esrc    = (const int*)d_in[2];
    const int* edst    = (const int*)d_in[3];
    float* out = (float*)d_out;

    int n_nodes = in_sizes[0] / D_FEAT;   // 100000
    int n_edges = in_sizes[1];            // 1600000

    int nb_buckets = (n_nodes + NPB - 1) / NPB;          // 782
    int n_scan = nb_buckets * NL1 + 1;                   // 200193
    int nbs = (n_scan + SCAN_CHUNK - 1) / SCAN_CHUNK;    // 98

    // ws: counts_T[n_scan] | partials[256] | node_start[n+1] | pad | elistA | elistB | (bfrow)
    size_t head_ints = (size_t)n_scan + 256 + (size_t)n_nodes + 1;
    size_t elist_off = (head_ints * 4 + 255) & ~(size_t)255;
    size_t elist_bytes = (size_t)n_edges * 8;
    size_t needed_base = elist_off + 2 * elist_bytes;
    size_t bf_bytes = (size_t)n_nodes * (D_FEAT * 2);    // 128B per row
    size_t needed_ded = needed_base + bf_bytes;

    bool sort_ok = (ws_size >= needed_base) && (nb_buckets <= MAX_NB) &&
                   (n_nodes <= (1 << SRC_BITS)) && (nbs <= 256);
    bool bf_ded = sort_ok && (ws_size >= needed_ded);
    bool bf_ovl = sort_ok && !bf_ded && (bf_bytes <= elist_bytes);  // reuse elistA

    if (sort_ok) {
        int* counts_T   = (int*)d_ws;
        int* partials   = counts_T + n_scan;
        int* node_start = partials + 256;
        int2* elistA    = (int2*)((char*)d_ws + elist_off);
        int2* elistB    = elistA + n_edges;

        mp_l1hist_kernel<<<NL1, 256, 0, stream>>>(edst, counts_T, n_edges, nb_buckets);
        mp_scan1_kernel<<<nbs, SCAN_T, 0, stream>>>(counts_T, partials, n_scan);
        mp_scan3_kernel<<<nbs, SCAN_T, 0, stream>>>(counts_T, partials, n_scan);
        mp_l1scatter_kernel<<<NL1, 256, 0, stream>>>(esrc, edst, ew, counts_T,
                                                     elistA, n_edges, nb_buckets);
        mp_l2sort_kernel<<<nb_buckets, 256, 0, stream>>>(
            elistA, counts_T, elistB, node_start, n_nodes, n_edges, nb_buckets);

        long long total = (long long)n_nodes * 64;
        if (bf_ded || bf_ovl) {
            uint_t* bfrow = bf_ded ? (uint_t*)((char*)d_ws + needed_base)
                                   : (uint_t*)elistA;   // elistA dead after l2sort
            int ncvt = n_nodes * (D_FEAT / 2);
            mp_cvt_kernel<<<(ncvt + 255) / 256, 256, 0, stream>>>(
                (const float2*)input, bfrow, ncvt);
            mp_gather3_kernel<<<(int)((total + 255) / 256), 256, 0, stream>>>(
                input, bfrow, node_start, elistB, out, n_nodes);
        } else {
            mp_gather2_kernel<<<(int)((total + 255) / 256), 256, 0, stream>>>(
                input, node_start, elistB, out, n_nodes);
        }
    } else {
        int n4 = (n_nodes * D_FEAT) / 4;
        mp_copy_kernel<<<(n4 + 255) / 256, 256, 0, stream>>>(
            (const float4*)input, (float4*)out, n4);
        long long total = (long long)n_edges * 64;
        mp_scatter_kernel<<<(int)((total + 255) / 256), 256, 0, stream>>>(
            input, ew, esrc, edst, out, n_edges);
    }
}